// Round 6
// baseline (80.275 us; speedup 1.0000x reference)
//
#include <hip/hip_runtime.h>
#include <hip/hip_bf16.h>

// Problem: B=2, N=1024, D=30, H=64, O=30  (all fp32)
//   zi = z @ W_r[:D], zj = z @ W_r[D:]
//   r_sum[b,i,h] = sum_j relu(zi[b,i,h] + zj[b,j,h] + b_r[h])
//   out[b,i,o]   = relu(sum_h r_sum[b,i,h]*W_a[h,o] + b_a[o])
//
// R5 post-mortem: hipLaunchCooperativeKernel breaks harness graph capture.
// Reverted to the proven R4 two-kernel structure (79.6 us).
// R6 change: relu(x) = (x+|x|)/2 identity. Inner loop accumulates sum|x|
// (abs is a free VOP3 modifier: v_add_f32 acc, |t|, acc), the linear term
// N*zi + S (S = sum_j zjb) is O(1) per (i,h): S accumulated during staging
// (nearly free), combined before the epilogue. Inner: 5 -> 4 issue slots/j.

#define BB 2
#define NN 1024
#define DD 30
#define HH 64
#define OO 30
#define JT 128      // j-tile rows staged in LDS per half (32 KB)
#define ITILE 8     // i rows per block

typedef float v2f __attribute__((ext_vector_type(2)));

// Kernel A: compute zi[b,n,h] and zjb[b,n,h] = zj + b_r  (b_r folded here)
__global__ __launch_bounds__(256) void proj_kernel(
    const float* __restrict__ z,    // [B*N, D]
    const float* __restrict__ Wr,   // [2D, H]
    const float* __restrict__ br,   // [H]
    float* __restrict__ zi_out,     // [B*N, H]
    float* __restrict__ zjb_out)    // [B*N, H]
{
    const int h = threadIdx.x;                      // 0..63
    const int r = blockIdx.x * 4 + threadIdx.y;     // row in [0, B*N)
    const float* zrow = z + (size_t)r * DD;
    float wi = 0.f, wj = 0.f;
#pragma unroll
    for (int d = 0; d < DD; ++d) {
        const float zv = zrow[d];                   // wave-uniform (scalar)
        wi += zv * Wr[d * HH + h];                  // coalesced across lanes
        wj += zv * Wr[(DD + d) * HH + h];
    }
    zi_out [(size_t)r * HH + h] = wi;
    zjb_out[(size_t)r * HH + h] = wj + br[h];
}

// Kernel B: abs-sum over j + linear term + fused H->O epilogue.
// Grid: (N/ITILE, B). Block: (64, 8) = 512 threads, 8 waves (2/SIMD).
// Waves 0-3 (half 0): j in [0,512); waves 4-7 (half 1): j in [512,1024).
__global__ __launch_bounds__(512) void pairsum_kernel(
    const float* __restrict__ zi,    // [B*N, H]
    const float* __restrict__ zjb,   // [B*N, H]
    const float* __restrict__ Wa,    // [H, O]
    const float* __restrict__ ba,    // [O]
    float* __restrict__ out)         // [B*N, O]
{
    __shared__ float sj[2][JT * HH];        // 2 x 32 KB j-tiles
    __shared__ float racc[2][ITILE][HH];    // 2 x 2 KB abs-sum partials
    __shared__ float Svec[HH];              // S[h] = sum_j zjb[j,h]

    const int h  = threadIdx.x;          // 0..63
    const int w  = threadIdx.y;          // 0..7
    const int hf = w >> 2;               // j-half: 0 or 1
    const int wq = w & 3;                // wave-quad index within half
    const int t4 = wq * 64 + h;          // 0..255 within half
    const int bt = w * 64 + h;           // 0..511 block-thread id
    const int b  = blockIdx.y;
    const int i0 = blockIdx.x * ITILE;

    const float* zbase = zi + ((size_t)b * NN + i0) * HH;
    v2f zv;
    zv.x = zbase[(wq * 2 + 0) * HH + h];
    zv.y = zbase[(wq * 2 + 1) * HH + h];
    v2f acc = {0.f, 0.f};                // sum |zi + zjb| for 2 i-rows
    float4 Sacc = {0.f, 0.f, 0.f, 0.f};  // S partial (fixed h-quad = t4%16)

    // this half's 512-row slab of zjb
    const float* slab = zjb + ((size_t)b * NN + hf * (NN / 2)) * HH;

    for (int tile = 0; tile < (NN / 2) / JT; ++tile) {
        // cooperative stage: JT*HH = 8192 floats = 2048 float4, 8/thread
        const float4* src = (const float4*)(slab + (size_t)tile * JT * HH);
        float4* dst = (float4*)sj[hf];
#pragma unroll
        for (int k = 0; k < 8; ++k) {
            const float4 v = src[t4 + k * 256];
            dst[t4 + k * 256] = v;
            Sacc.x += v.x; Sacc.y += v.y; Sacc.z += v.z; Sacc.w += v.w;
        }
        __syncthreads();
        const float* sjt = sj[hf];
#pragma unroll 8
        for (int j = 0; j < JT; ++j) {
            const float zjv = sjt[j * HH + h];   // 2-way bank alias: free
            v2f tt = zv + zjv;                   // packable: v_pk_add_f32
            acc.x += fabsf(tt.x);                // v_add_f32 with |src| mod
            acc.y += fabsf(tt.y);
        }
        __syncthreads();
    }

    // ---- combine: A partials, S reduction ----
    racc[hf][wq * 2 + 0][h] = acc.x;
    racc[hf][wq * 2 + 1][h] = acc.y;
    // Sred overlays sj[0] (all tile reads completed above)
    float* Sred = sj[0];                 // [512][4] floats used
    ((float4*)Sred)[bt] = Sacc;
    __syncthreads();

    if (bt < HH) {                       // lane h computes S[h]
        const int hq = bt >> 2, c = bt & 3;
        float s = 0.f;
#pragma unroll
        for (int m = 0; m < 16; ++m)     // 16 contributors per half
            s += Sred[(0 * 256 + hq + 16 * m) * 4 + c]
               + Sred[(1 * 256 + hq + 16 * m) * 4 + c];
        Svec[bt] = s;
    }
    __syncthreads();

    // ---- r_sum = 0.5*(N*zi + S + A), written into racc[0] ----
    {
        const int i = bt >> 6;           // 0..7
        const int hh = bt & 63;
        const float ziv = zbase[i * HH + hh];          // L2-hot, coalesced
        const float A = racc[0][i][hh] + racc[1][i][hh];
        racc[0][i][hh] = 0.5f * ((float)NN * ziv + Svec[hh] + A);
    }
    __syncthreads();

    // Epilogue: 8 rows x 30 outputs = 240 dots of length 64 (threads bt<256)
    const int i = bt >> 5;        // 0..7 for bt<256
    const int o = bt & 31;        // 0..31
    if (bt < 256 && o < OO) {
        float s = ba[o];
#pragma unroll
        for (int hh = 0; hh < HH; ++hh)
            s += racc[0][i][hh] * Wa[hh * OO + o];
        out[((size_t)b * NN + i0 + i) * OO + o] = fmaxf(s, 0.f);
    }
}

extern "C" void kernel_launch(void* const* d_in, const int* in_sizes, int n_in,
                              void* d_out, int out_size, void* d_ws, size_t ws_size,
                              hipStream_t stream) {
    const float* z_t = (const float*)d_in[0];   // [B,N,D]
    const float* W_r = (const float*)d_in[1];   // [2D,H]
    const float* b_r = (const float*)d_in[2];   // [H]
    const float* W_a = (const float*)d_in[3];   // [H,O]
    const float* b_a = (const float*)d_in[4];   // [O]
    float* out = (float*)d_out;                 // [B,N,O]

    float* zi  = (float*)d_ws;                  // B*N*H floats
    float* zjb = zi + (size_t)BB * NN * HH;     // B*N*H floats (1 MB total)

    proj_kernel<<<dim3((BB * NN) / 4), dim3(64, 4), 0, stream>>>(
        z_t, W_r, b_r, zi, zjb);
    pairsum_kernel<<<dim3(NN / ITILE, BB), dim3(64, 8), 0, stream>>>(
        zi, zjb, W_a, b_a, out);
}